// Round 1
// baseline (403.804 us; speedup 1.0000x reference)
//
#include <hip/hip_runtime.h>

typedef unsigned short u16;
typedef __attribute__((ext_vector_type(8))) short bf16x8;
typedef __attribute__((ext_vector_type(4))) float f32x4;

__device__ inline u16 f2bf(float f) {
  unsigned int u = __float_as_uint(f);
  u += 0x7fffu + ((u >> 16) & 1u);
  return (u16)(u >> 16);
}
__device__ inline float bf2f(u16 h) { return __uint_as_float(((unsigned int)h) << 16); }

__device__ inline void gload_lds16(const void* gp, void* lp) {
  __builtin_amdgcn_global_load_lds(
      (const __attribute__((address_space(1))) unsigned int*)gp,
      (__attribute__((address_space(3))) unsigned int*)lp, 16, 0, 0);
}

// ---------------- LayerNorm: f32 [rows][1024] -> bf16 ----------------
__global__ __launch_bounds__(256) void ln_kernel(const float* __restrict__ x,
                                                 const float* __restrict__ g,
                                                 const float* __restrict__ beta,
                                                 u16* __restrict__ y) {
  __shared__ float red[8];
  const int row = blockIdx.x;
  const int t = threadIdx.x;
  const float4 xv = *(const float4*)(x + (long)row * 1024 + t * 4);
  float s = xv.x + xv.y + xv.z + xv.w;
  float sq = xv.x * xv.x + xv.y * xv.y + xv.z * xv.z + xv.w * xv.w;
#pragma unroll
  for (int d = 1; d < 64; d <<= 1) {
    s += __shfl_xor(s, d);
    sq += __shfl_xor(sq, d);
  }
  if ((t & 63) == 0) { red[t >> 6] = s; red[4 + (t >> 6)] = sq; }
  __syncthreads();
  s = red[0] + red[1] + red[2] + red[3];
  sq = red[4] + red[5] + red[6] + red[7];
  const float mean = s * (1.f / 1024.f);
  const float var = sq * (1.f / 1024.f) - mean * mean;
  const float inv = rsqrtf(var + 1e-5f);
  float xe[4] = {xv.x, xv.y, xv.z, xv.w};
  u16 ov[4];
#pragma unroll
  for (int e = 0; e < 4; ++e)
    ov[e] = f2bf((xe[e] - mean) * inv * g[t * 4 + e] + beta[t * 4 + e]);
  *(unsigned long long*)(y + (long)row * 1024 + t * 4) = *(unsigned long long*)ov;
}

// ------------- transpose + convert: f32 in[R][C] -> bf16 out[C][R] -------------
__global__ __launch_bounds__(256) void transpose_bf16(const float* __restrict__ in,
                                                      u16* __restrict__ out,
                                                      int R, int C) {
  __shared__ float tile[32][33];
  const int tx = threadIdx.x & 31, ty = threadIdx.x >> 5;
  const int c0 = blockIdx.x * 32, r0 = blockIdx.y * 32;
#pragma unroll
  for (int i = 0; i < 4; ++i)
    tile[ty + i * 8][tx] = in[(long)(r0 + ty + i * 8) * C + c0 + tx];
  __syncthreads();
#pragma unroll
  for (int i = 0; i < 4; ++i)
    out[(long)(c0 + ty + i * 8) * R + r0 + tx] = f2bf(tile[tx][ty + i * 8]);
}

// ------------- RoPE + split: qkv f32 [rows][3072] -> q,k (rotated, q scaled), v bf16 -------------
__global__ __launch_bounds__(256) void rope_kernel(const float* __restrict__ qkv,
                                                   u16* __restrict__ qr,
                                                   u16* __restrict__ kr,
                                                   u16* __restrict__ vv) {
  const int row = blockIdx.x;            // b*2048 + s
  const int s = row & 2047;
  const int t = threadIdx.x;
  const float* base = qkv + (long)row * 3072;
  const long orow = (long)row * 1024;
#pragma unroll
  for (int rep = 0; rep < 2; ++rep) {
    const int p = rep * 256 + t;         // 0..511 : h*32 + d0
    const int h = p >> 5, d0 = p & 31;
    // inv_freq = 10000^(-d0/32), via exp2f for precision (log2(10000)=13.2877123795)
    const float inv = exp2f((float)d0 * (-13.287712379549449f / 32.f));
    const float ang = (float)s * inv;
    float sn, cs;
    sincosf(ang, &sn, &cs);
    const int c1 = h * 64 + d0, c2 = c1 + 32;
    float x1 = base[c1], x2 = base[c2];
    qr[orow + c1] = f2bf((x1 * cs - x2 * sn) * 0.125f);   // fold hd^-0.5
    qr[orow + c2] = f2bf((x2 * cs + x1 * sn) * 0.125f);
    float y1 = base[1024 + c1], y2 = base[1024 + c2];
    kr[orow + c1] = f2bf(y1 * cs - y2 * sn);
    kr[orow + c2] = f2bf(y2 * cs + y1 * sn);
  }
#pragma unroll
  for (int rep = 0; rep < 4; ++rep) {
    const int d = rep * 256 + t;
    vv[orow + d] = f2bf(base[2048 + d]);
  }
}

// ------------- local-causal flash attention, window 256, hd=64, H=16 -------------
// grid: b*512 + h*32 + qt  (qt over 64-query tiles); 4 waves x 16 query rows
__global__ __launch_bounds__(256) void attn_kernel(const u16* __restrict__ qr,
                                                   const u16* __restrict__ kr,
                                                   const u16* __restrict__ vv,
                                                   u16* __restrict__ o) {
  __shared__ __attribute__((aligned(16))) u16 Ks[320][72];   // padded rows
  __shared__ __attribute__((aligned(16))) u16 Vt[64][336];   // V transposed, padded
  __shared__ __attribute__((aligned(16))) u16 Pl[4][16][40]; // per-wave P buffer

  const int blk = blockIdx.x;
  const int qt = blk & 31;
  const int h = (blk >> 5) & 15;
  const int b = blk >> 9;
  const int qs = qt * 64;
  const int jbase = qs - 256;
  const int t = threadIdx.x;
  const int w = t >> 6, l = t & 63;
  const int lr = l & 15, lg = l >> 4;
  const long bh = (long)b * 2048 * 1024 + h * 64;

  // stage K: 320 rows x 64 bf16 (zero-fill j<0)
#pragma unroll
  for (int it = 0; it < 10; ++it) {
    const int c = it * 256 + t;
    const int jj = c >> 3, c8 = c & 7;
    const int jg = jbase + jj;
    bf16x8 val;
#pragma unroll
    for (int e = 0; e < 8; ++e) val[e] = 0;
    if (jg >= 0) val = *(const bf16x8*)(kr + bh + (long)jg * 1024 + c8 * 8);
    *(bf16x8*)(&Ks[jj][c8 * 8]) = val;
  }
  // stage V transposed: Vt[d][j]
#pragma unroll
  for (int it = 0; it < 10; ++it) {
    const int c = it * 256 + t;
    const int jj = c % 320, c8 = c / 320;
    const int jg = jbase + jj;
    if (jg >= 0) {
      bf16x8 val = *(const bf16x8*)(vv + bh + (long)jg * 1024 + c8 * 8);
#pragma unroll
      for (int e = 0; e < 8; ++e) Vt[c8 * 8 + e][jj] = (u16)val[e];
    } else {
#pragma unroll
      for (int e = 0; e < 8; ++e) Vt[c8 * 8 + e][jj] = 0;
    }
  }

  // Q fragments in registers (rows qs + w*16 .. +16)
  const int wq0 = w * 16;
  const u16* qp = qr + bh + (long)(qs + wq0 + lr) * 1024 + lg * 8;
  const bf16x8 aq0 = *(const bf16x8*)qp;
  const bf16x8 aq1 = *(const bf16x8*)(qp + 32);

  __syncthreads();

  f32x4 oacc[4];
#pragma unroll
  for (int nt = 0; nt < 4; ++nt) { oacc[nt][0] = 0.f; oacc[nt][1] = 0.f; oacc[nt][2] = 0.f; oacc[nt][3] = 0.f; }
  float m_[4], ls[4];
#pragma unroll
  for (int r = 0; r < 4; ++r) { m_[r] = -1e30f; ls[r] = 0.f; }

  const int qmaxw = qs + wq0 + 15;
  for (int ch = 0; ch < 10; ++ch) {
    const int j0 = ch * 32;
    const int jg0 = jbase + j0;
    if (jg0 + 31 < 0) continue;   // entire chunk below j=0
    if (jg0 > qmaxw) break;       // entire chunk beyond causal bound for this wave

    // S = Q K^T (two 16x16 tiles over 32 keys, K-dim 64 in two halves)
    f32x4 s0, s1;
    {
      f32x4 z; z[0] = z[1] = z[2] = z[3] = 0.f;
      const u16* kp0 = &Ks[j0 + lr][lg * 8];
      bf16x8 b0 = *(const bf16x8*)kp0;
      bf16x8 b1 = *(const bf16x8*)(kp0 + 32);
      s0 = __builtin_amdgcn_mfma_f32_16x16x32_bf16(aq0, b0, z, 0, 0, 0);
      s0 = __builtin_amdgcn_mfma_f32_16x16x32_bf16(aq1, b1, s0, 0, 0, 0);
      const u16* kp1 = &Ks[j0 + 16 + lr][lg * 8];
      b0 = *(const bf16x8*)kp1;
      b1 = *(const bf16x8*)(kp1 + 32);
      s1 = __builtin_amdgcn_mfma_f32_16x16x32_bf16(aq0, b0, z, 0, 0, 0);
      s1 = __builtin_amdgcn_mfma_f32_16x16x32_bf16(aq1, b1, s1, 0, 0, 0);
    }
    const int jc0 = jg0 + lr;
    const int jc1 = jc0 + 16;
    float p0[4], p1[4], al[4];
#pragma unroll
    for (int r = 0; r < 4; ++r) {
      const int qg = qs + wq0 + lg * 4 + r;
      const bool v0 = (jc0 >= 0) & (jc0 <= qg) & (qg - jc0 <= 256);
      const bool v1 = (jc1 >= 0) & (jc1 <= qg) & (qg - jc1 <= 256);
      const float t0 = v0 ? s0[r] : -1e30f;
      const float t1 = v1 ? s1[r] : -1e30f;
      float mx = fmaxf(t0, t1);
      mx = fmaxf(mx, __shfl_xor(mx, 1));
      mx = fmaxf(mx, __shfl_xor(mx, 2));
      mx = fmaxf(mx, __shfl_xor(mx, 4));
      mx = fmaxf(mx, __shfl_xor(mx, 8));
      const float mn = fmaxf(m_[r], mx);
      if (mn < -1e29f) {            // nothing valid yet for this row
        al[r] = 1.f; p0[r] = 0.f; p1[r] = 0.f;
      } else {
        al[r] = __expf(m_[r] - mn);
        p0[r] = (t0 < -1e29f) ? 0.f : __expf(t0 - mn);
        p1[r] = (t1 < -1e29f) ? 0.f : __expf(t1 - mn);
      }
      m_[r] = mn;
      float rs = p0[r] + p1[r];
      rs += __shfl_xor(rs, 1);
      rs += __shfl_xor(rs, 2);
      rs += __shfl_xor(rs, 4);
      rs += __shfl_xor(rs, 8);
      ls[r] = ls[r] * al[r] + rs;
    }
    // P (C-layout) -> per-wave LDS -> A-fragment
#pragma unroll
    for (int r = 0; r < 4; ++r) {
      Pl[w][lg * 4 + r][lr] = f2bf(p0[r]);
      Pl[w][lg * 4 + r][lr + 16] = f2bf(p1[r]);
    }
    asm volatile("s_waitcnt lgkmcnt(0)" ::: "memory");
    const bf16x8 pa = *(const bf16x8*)(&Pl[w][lr][lg * 8]);
#pragma unroll
    for (int nt = 0; nt < 4; ++nt) {
      f32x4 oa = oacc[nt];
#pragma unroll
      for (int r = 0; r < 4; ++r) oa[r] *= al[r];
      const bf16x8 bv = *(const bf16x8*)(&Vt[nt * 16 + lr][j0 + lg * 8]);
      oacc[nt] = __builtin_amdgcn_mfma_f32_16x16x32_bf16(pa, bv, oa, 0, 0, 0);
    }
  }
  // normalize + store (o layout [b,s,h*64+d])
#pragma unroll
  for (int nt = 0; nt < 4; ++nt)
#pragma unroll
    for (int r = 0; r < 4; ++r) {
      const long qg = qs + wq0 + lg * 4 + r;
      o[bh + qg * 1024 + nt * 16 + lr] = f2bf(oacc[nt][r] / ls[r]);
    }
}

// ------------- bf16 GEMM, B pre-transposed: C[M,N] = A[M,K] * BT[N,K]^T -------------
// EPI: 0=store f32, 1=f32 +res, 2=bf16 +bias, 3=bf16 gate*silu(acc+bias), 4=f32 +bias+res
template <int EPI>
__global__ __launch_bounds__(256) void gemm_bt(const u16* __restrict__ A,
                                               const u16* __restrict__ BT,
                                               float* __restrict__ Cf,
                                               u16* __restrict__ Cb,
                                               const float* __restrict__ bias,
                                               const float* __restrict__ res,
                                               const u16* __restrict__ gate,
                                               int M, int N, int K) {
  __shared__ __attribute__((aligned(16))) u16 As[128 * 32];
  __shared__ __attribute__((aligned(16))) u16 Bs[128 * 32];
  const int t = threadIdx.x;
  const int w = t >> 6, l = t & 63;
  const int lr = l & 15, lg = l >> 4;
  const int wm = (w >> 1) * 64, wn = (w & 1) * 64;
  const long m0 = (long)blockIdx.y * 128, n0 = (long)blockIdx.x * 128;

  f32x4 acc[4][4];
#pragma unroll
  for (int i = 0; i < 4; ++i)
#pragma unroll
    for (int j = 0; j < 4; ++j) { acc[i][j][0] = 0.f; acc[i][j][1] = 0.f; acc[i][j][2] = 0.f; acc[i][j][3] = 0.f; }

  const int row0 = t >> 2, k80 = (t & 3) << 3;              // chunk t
  const int row1 = (256 + t) >> 2, k81 = ((256 + t) & 3) << 3; // chunk 256+t
  const u16* Ab = A + m0 * K;
  const u16* Bb = BT + n0 * K;

  for (int kt = 0; kt < K; kt += 32) {
    __syncthreads();
    gload_lds16(Ab + (long)row0 * K + kt + k80, (u16*)As + (w * 64) * 8);
    gload_lds16(Ab + (long)row1 * K + kt + k81, (u16*)As + (256 + w * 64) * 8);
    gload_lds16(Bb + (long)row0 * K + kt + k80, (u16*)Bs + (w * 64) * 8);
    gload_lds16(Bb + (long)row1 * K + kt + k81, (u16*)Bs + (256 + w * 64) * 8);
    __syncthreads();
    bf16x8 af[4], bfr[4];
#pragma unroll
    for (int i = 0; i < 4; ++i)
      af[i] = *(const bf16x8*)(As + (wm + i * 16 + lr) * 32 + lg * 8);
#pragma unroll
    for (int j = 0; j < 4; ++j)
      bfr[j] = *(const bf16x8*)(Bs + (wn + j * 16 + lr) * 32 + lg * 8);
#pragma unroll
    for (int i = 0; i < 4; ++i)
#pragma unroll
      for (int j = 0; j < 4; ++j)
        acc[i][j] = __builtin_amdgcn_mfma_f32_16x16x32_bf16(af[i], bfr[j], acc[i][j], 0, 0, 0);
  }

#pragma unroll
  for (int i = 0; i < 4; ++i) {
    const long mr = m0 + wm + i * 16 + lg * 4;
#pragma unroll
    for (int j = 0; j < 4; ++j) {
      const long nc = n0 + wn + j * 16 + lr;
#pragma unroll
      for (int r = 0; r < 4; ++r) {
        const long idx = (mr + r) * N + nc;
        const float v = acc[i][j][r];
        if constexpr (EPI == 0) {
          Cf[idx] = v;
        } else if constexpr (EPI == 1) {
          Cf[idx] = v + res[idx];
        } else if constexpr (EPI == 2) {
          Cb[idx] = f2bf(v + bias[nc]);
        } else if constexpr (EPI == 3) {
          const float u = v + bias[nc];
          const float sg = 1.f / (1.f + __expf(-u));
          Cb[idx] = f2bf(bf2f(gate[idx]) * u * sg);
        } else {
          Cf[idx] = v + bias[nc] + res[idx];
        }
      }
    }
  }
}

extern "C" void kernel_launch(void* const* d_in, const int* in_sizes, int n_in,
                              void* d_out, int out_size, void* d_ws, size_t ws_size,
                              hipStream_t stream) {
  (void)in_sizes; (void)n_in; (void)out_size; (void)ws_size;
  const float* x      = (const float*)d_in[0];
  const float* w_qkv  = (const float*)d_in[1];
  const float* w_out  = (const float*)d_in[2];
  const float* g1     = (const float*)d_in[3];
  const float* b1     = (const float*)d_in[4];
  const float* g2     = (const float*)d_in[5];
  const float* b2     = (const float*)d_in[6];
  const float* w_gate = (const float*)d_in[7];
  const float* b_gate = (const float*)d_in[8];
  const float* w_up   = (const float*)d_in[9];
  const float* b_up   = (const float*)d_in[10];
  const float* w_down = (const float*)d_in[11];
  const float* b_down = (const float*)d_in[12];
  float* out = (float*)d_out;

  const size_t MB = 1u << 20;
  char* ws = (char*)d_ws;
  u16*   y      = (u16*)(ws + 0 * MB);    // [4096][1024] bf16 (y1 then y2)
  u16*   wqkvT  = (u16*)(ws + 8 * MB);    // [3072][1024]
  u16*   woutT  = (u16*)(ws + 14 * MB);   // [1024][1024]
  u16*   wgateT = (u16*)(ws + 16 * MB);   // [4096][1024]
  u16*   wupT   = (u16*)(ws + 24 * MB);   // [4096][1024]
  u16*   wdownT = (u16*)(ws + 32 * MB);   // [1024][4096]
  float* qkv    = (float*)(ws + 40 * MB); // [4096][3072] f32 (48MB)
  u16*   qr_    = (u16*)(ws + 88 * MB);   // [4096][1024]
  u16*   kr_    = (u16*)(ws + 96 * MB);
  u16*   vv_    = (u16*)(ws + 104 * MB);
  u16*   o_     = (u16*)(ws + 112 * MB);
  float* x1     = (float*)(ws + 120 * MB); // [4096][1024] f32 (16MB)
  u16*   gbuf   = (u16*)(ws + 40 * MB);    // alias qkv (dead after rope) [4096][4096]
  u16*   gated  = (u16*)(ws + 88 * MB);    // alias qr/kr/vv/o (dead after attn/out-proj)

  const dim3 blk(256);
  // weight transposes (f32 [K,N] -> bf16 [N,K])
  transpose_bf16<<<dim3(3072 / 32, 1024 / 32), blk, 0, stream>>>(w_qkv, wqkvT, 1024, 3072);
  transpose_bf16<<<dim3(1024 / 32, 1024 / 32), blk, 0, stream>>>(w_out, woutT, 1024, 1024);
  transpose_bf16<<<dim3(4096 / 32, 1024 / 32), blk, 0, stream>>>(w_gate, wgateT, 1024, 4096);
  transpose_bf16<<<dim3(4096 / 32, 1024 / 32), blk, 0, stream>>>(w_up, wupT, 1024, 4096);
  transpose_bf16<<<dim3(1024 / 32, 4096 / 32), blk, 0, stream>>>(w_down, wdownT, 4096, 1024);

  // LN1
  ln_kernel<<<4096, blk, 0, stream>>>(x, g1, b1, y);
  // QKV projection
  gemm_bt<0><<<dim3(3072 / 128, 4096 / 128), blk, 0, stream>>>(
      y, wqkvT, qkv, nullptr, nullptr, nullptr, nullptr, 4096, 3072, 1024);
  // RoPE + bf16 split
  rope_kernel<<<4096, blk, 0, stream>>>(qkv, qr_, kr_, vv_);
  // local-causal attention
  attn_kernel<<<1024, blk, 0, stream>>>(qr_, kr_, vv_, o_);
  // out-proj + residual
  gemm_bt<1><<<dim3(1024 / 128, 4096 / 128), blk, 0, stream>>>(
      o_, woutT, x1, nullptr, nullptr, x, nullptr, 4096, 1024, 1024);
  // LN2
  ln_kernel<<<4096, blk, 0, stream>>>(x1, g2, b2, y);
  // gate = y*w_gate + b_gate (bf16)
  gemm_bt<2><<<dim3(4096 / 128, 4096 / 128), blk, 0, stream>>>(
      y, wgateT, nullptr, gbuf, b_gate, nullptr, nullptr, 4096, 4096, 1024);
  // gated = gate * silu(y*w_up + b_up) (bf16)
  gemm_bt<3><<<dim3(4096 / 128, 4096 / 128), blk, 0, stream>>>(
      y, wupT, nullptr, gated, b_up, nullptr, gbuf, 4096, 4096, 1024);
  // out = x1 + gated*w_down + b_down (f32)
  gemm_bt<4><<<dim3(1024 / 128, 4096 / 128), blk, 0, stream>>>(
      gated, wdownT, out, nullptr, b_down, x1, nullptr, 4096, 1024, 4096);
}

// Round 2
// 402.972 us; speedup vs baseline: 1.0021x; 1.0021x over previous
//
#include <hip/hip_runtime.h>

typedef unsigned short u16;
typedef __attribute__((ext_vector_type(8))) short bf16x8;
typedef __attribute__((ext_vector_type(4))) float f32x4;

__device__ inline u16 f2bf(float f) {
  unsigned int u = __float_as_uint(f);
  u += 0x7fffu + ((u >> 16) & 1u);
  return (u16)(u >> 16);
}
__device__ inline float bf2f(u16 h) { return __uint_as_float(((unsigned int)h) << 16); }

__device__ inline void gload_lds16(const void* gp, void* lp) {
  __builtin_amdgcn_global_load_lds(
      (const __attribute__((address_space(1))) unsigned int*)gp,
      (__attribute__((address_space(3))) unsigned int*)lp, 16, 0, 0);
}

// ---------------- LayerNorm: f32 [rows][1024] -> bf16 ----------------
__global__ __launch_bounds__(256) void ln_kernel(const float* __restrict__ x,
                                                 const float* __restrict__ g,
                                                 const float* __restrict__ beta,
                                                 u16* __restrict__ y) {
  __shared__ float red[8];
  const int row = blockIdx.x;
  const int t = threadIdx.x;
  const float4 xv = *(const float4*)(x + (long)row * 1024 + t * 4);
  float s = xv.x + xv.y + xv.z + xv.w;
  float sq = xv.x * xv.x + xv.y * xv.y + xv.z * xv.z + xv.w * xv.w;
#pragma unroll
  for (int d = 1; d < 64; d <<= 1) {
    s += __shfl_xor(s, d);
    sq += __shfl_xor(sq, d);
  }
  if ((t & 63) == 0) { red[t >> 6] = s; red[4 + (t >> 6)] = sq; }
  __syncthreads();
  s = red[0] + red[1] + red[2] + red[3];
  sq = red[4] + red[5] + red[6] + red[7];
  const float mean = s * (1.f / 1024.f);
  const float var = sq * (1.f / 1024.f) - mean * mean;
  const float inv = rsqrtf(var + 1e-5f);
  float xe[4] = {xv.x, xv.y, xv.z, xv.w};
  u16 ov[4];
#pragma unroll
  for (int e = 0; e < 4; ++e)
    ov[e] = f2bf((xe[e] - mean) * inv * g[t * 4 + e] + beta[t * 4 + e]);
  *(unsigned long long*)(y + (long)row * 1024 + t * 4) = *(unsigned long long*)ov;
}

// ------------- transpose + convert: f32 in[R][C] -> bf16 out[C][R] -------------
__global__ __launch_bounds__(256) void transpose_bf16(const float* __restrict__ in,
                                                      u16* __restrict__ out,
                                                      int R, int C) {
  __shared__ float tile[32][33];
  const int tx = threadIdx.x & 31, ty = threadIdx.x >> 5;
  const int c0 = blockIdx.x * 32, r0 = blockIdx.y * 32;
#pragma unroll
  for (int i = 0; i < 4; ++i)
    tile[ty + i * 8][tx] = in[(long)(r0 + ty + i * 8) * C + c0 + tx];
  __syncthreads();
#pragma unroll
  for (int i = 0; i < 4; ++i)
    out[(long)(c0 + ty + i * 8) * R + r0 + tx] = f2bf(tile[tx][ty + i * 8]);
}

// ------------- RoPE + split: qkv f32 [rows][3072] -> q,k (rotated, q scaled), v bf16 -------------
__global__ __launch_bounds__(256) void rope_kernel(const float* __restrict__ qkv,
                                                   u16* __restrict__ qr,
                                                   u16* __restrict__ kr,
                                                   u16* __restrict__ vv) {
  const int row = blockIdx.x;            // b*2048 + s
  const int s = row & 2047;
  const int t = threadIdx.x;
  const float* base = qkv + (long)row * 3072;
  const long orow = (long)row * 1024;
#pragma unroll
  for (int rep = 0; rep < 2; ++rep) {
    const int p = rep * 256 + t;         // 0..511 : h*32 + d0
    const int h = p >> 5, d0 = p & 31;
    // inv_freq = 10000^(-d0/32), via exp2f for precision (log2(10000)=13.2877123795)
    const float inv = exp2f((float)d0 * (-13.287712379549449f / 32.f));
    const float ang = (float)s * inv;
    float sn, cs;
    sincosf(ang, &sn, &cs);
    const int c1 = h * 64 + d0, c2 = c1 + 32;
    float x1 = base[c1], x2 = base[c2];
    qr[orow + c1] = f2bf((x1 * cs - x2 * sn) * 0.125f);   // fold hd^-0.5
    qr[orow + c2] = f2bf((x2 * cs + x1 * sn) * 0.125f);
    float y1 = base[1024 + c1], y2 = base[1024 + c2];
    kr[orow + c1] = f2bf(y1 * cs - y2 * sn);
    kr[orow + c2] = f2bf(y2 * cs + y1 * sn);
  }
#pragma unroll
  for (int rep = 0; rep < 4; ++rep) {
    const int d = rep * 256 + t;
    vv[orow + d] = f2bf(base[2048 + d]);
  }
}

// ------------- local-causal flash attention, window 256, hd=64, H=16 -------------
// grid: b*512 + h*32 + qt  (qt over 64-query tiles); 4 waves x 16 query rows
__global__ __launch_bounds__(256) void attn_kernel(const u16* __restrict__ qr,
                                                   const u16* __restrict__ kr,
                                                   const u16* __restrict__ vv,
                                                   u16* __restrict__ o) {
  __shared__ __attribute__((aligned(16))) u16 Ks[320][72];   // padded rows
  __shared__ __attribute__((aligned(16))) u16 Vt[64][336];   // V transposed, padded
  __shared__ __attribute__((aligned(16))) u16 Pl[4][16][40]; // per-wave P buffer

  const int blk = blockIdx.x;
  const int qt = blk & 31;
  const int h = (blk >> 5) & 15;
  const int b = blk >> 9;
  const int qs = qt * 64;
  const int jbase = qs - 256;
  const int t = threadIdx.x;
  const int w = t >> 6, l = t & 63;
  const int lr = l & 15, lg = l >> 4;
  const long bh = (long)b * 2048 * 1024 + h * 64;

  // stage K: 320 rows x 64 bf16 (zero-fill j<0)
#pragma unroll
  for (int it = 0; it < 10; ++it) {
    const int c = it * 256 + t;
    const int jj = c >> 3, c8 = c & 7;
    const int jg = jbase + jj;
    bf16x8 val;
#pragma unroll
    for (int e = 0; e < 8; ++e) val[e] = 0;
    if (jg >= 0) val = *(const bf16x8*)(kr + bh + (long)jg * 1024 + c8 * 8);
    *(bf16x8*)(&Ks[jj][c8 * 8]) = val;
  }
  // stage V transposed: Vt[d][j]
#pragma unroll
  for (int it = 0; it < 10; ++it) {
    const int c = it * 256 + t;
    const int jj = c % 320, c8 = c / 320;
    const int jg = jbase + jj;
    if (jg >= 0) {
      bf16x8 val = *(const bf16x8*)(vv + bh + (long)jg * 1024 + c8 * 8);
#pragma unroll
      for (int e = 0; e < 8; ++e) Vt[c8 * 8 + e][jj] = (u16)val[e];
    } else {
#pragma unroll
      for (int e = 0; e < 8; ++e) Vt[c8 * 8 + e][jj] = 0;
    }
  }

  // Q fragments in registers (rows qs + w*16 .. +16)
  const int wq0 = w * 16;
  const u16* qp = qr + bh + (long)(qs + wq0 + lr) * 1024 + lg * 8;
  const bf16x8 aq0 = *(const bf16x8*)qp;
  const bf16x8 aq1 = *(const bf16x8*)(qp + 32);

  __syncthreads();

  f32x4 oacc[4];
#pragma unroll
  for (int nt = 0; nt < 4; ++nt) { oacc[nt][0] = 0.f; oacc[nt][1] = 0.f; oacc[nt][2] = 0.f; oacc[nt][3] = 0.f; }
  float m_[4], ls[4];
#pragma unroll
  for (int r = 0; r < 4; ++r) { m_[r] = -1e30f; ls[r] = 0.f; }

  const int qmaxw = qs + wq0 + 15;
  for (int ch = 0; ch < 10; ++ch) {
    const int j0 = ch * 32;
    const int jg0 = jbase + j0;
    if (jg0 + 31 < 0) continue;   // entire chunk below j=0
    if (jg0 > qmaxw) break;       // entire chunk beyond causal bound for this wave

    // S = Q K^T (two 16x16 tiles over 32 keys, K-dim 64 in two halves)
    f32x4 s0, s1;
    {
      f32x4 z; z[0] = z[1] = z[2] = z[3] = 0.f;
      const u16* kp0 = &Ks[j0 + lr][lg * 8];
      bf16x8 b0 = *(const bf16x8*)kp0;
      bf16x8 b1 = *(const bf16x8*)(kp0 + 32);
      s0 = __builtin_amdgcn_mfma_f32_16x16x32_bf16(aq0, b0, z, 0, 0, 0);
      s0 = __builtin_amdgcn_mfma_f32_16x16x32_bf16(aq1, b1, s0, 0, 0, 0);
      const u16* kp1 = &Ks[j0 + 16 + lr][lg * 8];
      b0 = *(const bf16x8*)kp1;
      b1 = *(const bf16x8*)(kp1 + 32);
      s1 = __builtin_amdgcn_mfma_f32_16x16x32_bf16(aq0, b0, z, 0, 0, 0);
      s1 = __builtin_amdgcn_mfma_f32_16x16x32_bf16(aq1, b1, s1, 0, 0, 0);
    }
    const int jc0 = jg0 + lr;
    const int jc1 = jc0 + 16;
    float p0[4], p1[4], al[4];
#pragma unroll
    for (int r = 0; r < 4; ++r) {
      const int qg = qs + wq0 + lg * 4 + r;
      const bool v0 = (jc0 >= 0) & (jc0 <= qg) & (qg - jc0 <= 256);
      const bool v1 = (jc1 >= 0) & (jc1 <= qg) & (qg - jc1 <= 256);
      const float t0 = v0 ? s0[r] : -1e30f;
      const float t1 = v1 ? s1[r] : -1e30f;
      float mx = fmaxf(t0, t1);
      mx = fmaxf(mx, __shfl_xor(mx, 1));
      mx = fmaxf(mx, __shfl_xor(mx, 2));
      mx = fmaxf(mx, __shfl_xor(mx, 4));
      mx = fmaxf(mx, __shfl_xor(mx, 8));
      const float mn = fmaxf(m_[r], mx);
      if (mn < -1e29f) {            // nothing valid yet for this row
        al[r] = 1.f; p0[r] = 0.f; p1[r] = 0.f;
      } else {
        al[r] = __expf(m_[r] - mn);
        p0[r] = (t0 < -1e29f) ? 0.f : __expf(t0 - mn);
        p1[r] = (t1 < -1e29f) ? 0.f : __expf(t1 - mn);
      }
      m_[r] = mn;
      float rs = p0[r] + p1[r];
      rs += __shfl_xor(rs, 1);
      rs += __shfl_xor(rs, 2);
      rs += __shfl_xor(rs, 4);
      rs += __shfl_xor(rs, 8);
      ls[r] = ls[r] * al[r] + rs;
    }
    // P (C-layout) -> per-wave LDS -> A-fragment
#pragma unroll
    for (int r = 0; r < 4; ++r) {
      Pl[w][lg * 4 + r][lr] = f2bf(p0[r]);
      Pl[w][lg * 4 + r][lr + 16] = f2bf(p1[r]);
    }
    asm volatile("s_waitcnt lgkmcnt(0)" ::: "memory");
    const bf16x8 pa = *(const bf16x8*)(&Pl[w][lr][lg * 8]);
#pragma unroll
    for (int nt = 0; nt < 4; ++nt) {
      f32x4 oa = oacc[nt];
#pragma unroll
      for (int r = 0; r < 4; ++r) oa[r] *= al[r];
      const bf16x8 bv = *(const bf16x8*)(&Vt[nt * 16 + lr][j0 + lg * 8]);
      oacc[nt] = __builtin_amdgcn_mfma_f32_16x16x32_bf16(pa, bv, oa, 0, 0, 0);
    }
  }
  // normalize + store (o layout [b,s,h*64+d])
#pragma unroll
  for (int nt = 0; nt < 4; ++nt)
#pragma unroll
    for (int r = 0; r < 4; ++r) {
      const long qg = qs + wq0 + lg * 4 + r;
      o[bh + qg * 1024 + nt * 16 + lr] = f2bf(oacc[nt][r] / ls[r]);
    }
}

// ------------- bf16 GEMM, B pre-transposed: C[M,N] = A[M,K] * BT[N,K]^T -------------
// EPI: 0=store f32, 1=f32 +res, 2=bf16 +bias, 3=bf16 gate*silu(acc+bias), 4=f32 +bias+res
template <int EPI>
__global__ __launch_bounds__(256) void gemm_bt(const u16* __restrict__ A,
                                               const u16* __restrict__ BT,
                                               float* __restrict__ Cf,
                                               u16* __restrict__ Cb,
                                               const float* __restrict__ bias,
                                               const float* __restrict__ res,
                                               const u16* __restrict__ gate,
                                               int M, int N, int K) {
  __shared__ __attribute__((aligned(16))) u16 As[128 * 32];
  __shared__ __attribute__((aligned(16))) u16 Bs[128 * 32];
  const int t = threadIdx.x;
  const int w = t >> 6, l = t & 63;
  const int lr = l & 15, lg = l >> 4;
  const int wm = (w >> 1) * 64, wn = (w & 1) * 64;
  const long m0 = (long)blockIdx.y * 128, n0 = (long)blockIdx.x * 128;

  f32x4 acc[4][4];
#pragma unroll
  for (int i = 0; i < 4; ++i)
#pragma unroll
    for (int j = 0; j < 4; ++j) { acc[i][j][0] = 0.f; acc[i][j][1] = 0.f; acc[i][j][2] = 0.f; acc[i][j][3] = 0.f; }

  const int row0 = t >> 2, k80 = (t & 3) << 3;              // chunk t
  const int row1 = (256 + t) >> 2, k81 = ((256 + t) & 3) << 3; // chunk 256+t
  const u16* Ab = A + m0 * K;
  const u16* Bb = BT + n0 * K;

  for (int kt = 0; kt < K; kt += 32) {
    __syncthreads();
    gload_lds16(Ab + (long)row0 * K + kt + k80, (u16*)As + (w * 64) * 8);
    gload_lds16(Ab + (long)row1 * K + kt + k81, (u16*)As + (256 + w * 64) * 8);
    gload_lds16(Bb + (long)row0 * K + kt + k80, (u16*)Bs + (w * 64) * 8);
    gload_lds16(Bb + (long)row1 * K + kt + k81, (u16*)Bs + (256 + w * 64) * 8);
    __syncthreads();
    bf16x8 af[4], bfr[4];
#pragma unroll
    for (int i = 0; i < 4; ++i)
      af[i] = *(const bf16x8*)(As + (wm + i * 16 + lr) * 32 + lg * 8);
#pragma unroll
    for (int j = 0; j < 4; ++j)
      bfr[j] = *(const bf16x8*)(Bs + (wn + j * 16 + lr) * 32 + lg * 8);
#pragma unroll
    for (int i = 0; i < 4; ++i)
#pragma unroll
      for (int j = 0; j < 4; ++j)
        acc[i][j] = __builtin_amdgcn_mfma_f32_16x16x32_bf16(af[i], bfr[j], acc[i][j], 0, 0, 0);
  }

#pragma unroll
  for (int i = 0; i < 4; ++i) {
    const long mr = m0 + wm + i * 16 + lg * 4;
#pragma unroll
    for (int j = 0; j < 4; ++j) {
      const long nc = n0 + wn + j * 16 + lr;
#pragma unroll
      for (int r = 0; r < 4; ++r) {
        const long idx = (mr + r) * N + nc;
        const float v = acc[i][j][r];
        if constexpr (EPI == 0) {
          Cf[idx] = v;
        } else if constexpr (EPI == 1) {
          Cf[idx] = v + res[idx];
        } else if constexpr (EPI == 2) {
          Cb[idx] = f2bf(v + bias[nc]);
        } else if constexpr (EPI == 3) {
          const float u = v + bias[nc];
          const float sg = 1.f / (1.f + __expf(-u));
          Cb[idx] = f2bf(bf2f(gate[idx]) * u * sg);
        } else {
          Cf[idx] = v + bias[nc] + res[idx];
        }
      }
    }
  }
}

extern "C" void kernel_launch(void* const* d_in, const int* in_sizes, int n_in,
                              void* d_out, int out_size, void* d_ws, size_t ws_size,
                              hipStream_t stream) {
  (void)in_sizes; (void)n_in; (void)out_size; (void)ws_size;
  const float* x      = (const float*)d_in[0];
  const float* w_qkv  = (const float*)d_in[1];
  const float* w_out  = (const float*)d_in[2];
  const float* g1     = (const float*)d_in[3];
  const float* b1     = (const float*)d_in[4];
  const float* g2     = (const float*)d_in[5];
  const float* b2     = (const float*)d_in[6];
  const float* w_gate = (const float*)d_in[7];
  const float* b_gate = (const float*)d_in[8];
  const float* w_up   = (const float*)d_in[9];
  const float* b_up   = (const float*)d_in[10];
  const float* w_down = (const float*)d_in[11];
  const float* b_down = (const float*)d_in[12];
  float* out = (float*)d_out;

  const size_t MB = 1u << 20;
  char* ws = (char*)d_ws;
  u16*   y      = (u16*)(ws + 0 * MB);    // [4096][1024] bf16 (y1 then y2)
  u16*   wqkvT  = (u16*)(ws + 8 * MB);    // [3072][1024]
  u16*   woutT  = (u16*)(ws + 14 * MB);   // [1024][1024]
  u16*   wgateT = (u16*)(ws + 16 * MB);   // [4096][1024]
  u16*   wupT   = (u16*)(ws + 24 * MB);   // [4096][1024]
  u16*   wdownT = (u16*)(ws + 32 * MB);   // [1024][4096]
  float* qkv    = (float*)(ws + 40 * MB); // [4096][3072] f32 (48MB)
  u16*   qr_    = (u16*)(ws + 88 * MB);   // [4096][1024]
  u16*   kr_    = (u16*)(ws + 96 * MB);
  u16*   vv_    = (u16*)(ws + 104 * MB);
  u16*   o_     = (u16*)(ws + 112 * MB);
  float* x1     = (float*)(ws + 120 * MB); // [4096][1024] f32 (16MB)
  u16*   gbuf   = (u16*)(ws + 40 * MB);    // alias qkv (dead after rope) [4096][4096]
  u16*   gated  = (u16*)(ws + 88 * MB);    // alias qr/kr/vv/o (dead after attn/out-proj)

  const dim3 blk(256);
  // weight transposes (f32 [K,N] -> bf16 [N,K])
  transpose_bf16<<<dim3(3072 / 32, 1024 / 32), blk, 0, stream>>>(w_qkv, wqkvT, 1024, 3072);
  transpose_bf16<<<dim3(1024 / 32, 1024 / 32), blk, 0, stream>>>(w_out, woutT, 1024, 1024);
  transpose_bf16<<<dim3(4096 / 32, 1024 / 32), blk, 0, stream>>>(w_gate, wgateT, 1024, 4096);
  transpose_bf16<<<dim3(4096 / 32, 1024 / 32), blk, 0, stream>>>(w_up, wupT, 1024, 4096);
  transpose_bf16<<<dim3(1024 / 32, 4096 / 32), blk, 0, stream>>>(w_down, wdownT, 4096, 1024);

  // LN1
  ln_kernel<<<4096, blk, 0, stream>>>(x, g1, b1, y);
  // QKV projection
  gemm_bt<0><<<dim3(3072 / 128, 4096 / 128), blk, 0, stream>>>(
      y, wqkvT, qkv, nullptr, nullptr, nullptr, nullptr, 4096, 3072, 1024);
  // RoPE + bf16 split
  rope_kernel<<<4096, blk, 0, stream>>>(qkv, qr_, kr_, vv_);
  // local-causal attention
  attn_kernel<<<1024, blk, 0, stream>>>(qr_, kr_, vv_, o_);
  // out-proj + residual
  gemm_bt<1><<<dim3(1024 / 128, 4096 / 128), blk, 0, stream>>>(
      o_, woutT, x1, nullptr, nullptr, x, nullptr, 4096, 1024, 1024);
  // LN2
  ln_kernel<<<4096, blk, 0, stream>>>(x1, g2, b2, y);
  // gate = y*w_gate + b_gate (bf16)
  gemm_bt<2><<<dim3(4096 / 128, 4096 / 128), blk, 0, stream>>>(
      y, wgateT, nullptr, gbuf, b_gate, nullptr, nullptr, 4096, 4096, 1024);
  // gated = gate * silu(y*w_up + b_up) (bf16)
  gemm_bt<3><<<dim3(4096 / 128, 4096 / 128), blk, 0, stream>>>(
      y, wupT, nullptr, gated, b_up, nullptr, gbuf, 4096, 4096, 1024);
  // out = x1 + gated*w_down + b_down (f32)
  gemm_bt<4><<<dim3(1024 / 128, 4096 / 128), blk, 0, stream>>>(
      gated, wdownT, out, nullptr, b_down, x1, nullptr, 4096, 1024, 4096);
}